// Round 10
// baseline (2771.696 us; speedup 1.0000x reference)
//
#include <hip/hip_runtime.h>
#include <hip/hip_bf16.h>
#include <math.h>

#define I48 0.14433756729740643f  // 1/sqrt(48)
#define NKB 194                   // 6144 W rows + 64 bias rows, /32
#define KCH 4                     // kblks per LDS chunk (12 KiB fp16)
#define KSPL 6                    // K-split (proven optimum: 3 blocks/CU)

typedef __attribute__((ext_vector_type(8))) _Float16 half8;
typedef __attribute__((ext_vector_type(4))) float f32x4;

__device__ __forceinline__ float silu_f(float x){ return x / (1.f + __expf(-x)); }

// ---- DIY grid barrier (co-residency by construction: 768 blocks = 256CU x 3).
// All-threads release fence -> arrive -> acquire poll -> fence. Distinct slot
// per sync point; bars[] zeroed by the leading memset every replay. Bounded
// spin (escape ~0.17s) keeps it hang-proof: a barrier bug shows as wrong
// numerics, not a dead container.
__device__ __forceinline__ void gsync(int* bars, int slot, int nblk){
  __threadfence();                       // release: my block's writes -> device
  __syncthreads();
  if (threadIdx.x == 0){
    int* p = bars + slot;
    __hip_atomic_fetch_add(p, 1, __ATOMIC_RELEASE, __HIP_MEMORY_SCOPE_AGENT);
    int g = 0;
    while (__hip_atomic_load(p, __ATOMIC_ACQUIRE, __HIP_MEMORY_SCOPE_AGENT) < nblk){
      __builtin_amdgcn_s_sleep(2);
      if (++g > (1<<21)) break;          // hang-proof escape
    }
  }
  __syncthreads();
  __threadfence();                       // acquire: no stale reads after
}

// ---------------- time embedding (1 block, 128 thr) ----------------
__global__ void k_temb(const float* __restrict__ t_in,
                       const float* __restrict__ w1, const float* __restrict__ b1,
                       const float* __restrict__ w2, const float* __restrict__ b2,
                       const float* __restrict__ g,  const float* __restrict__ b,
                       float* __restrict__ temb){
  __shared__ float emb[64], h1[128], red[128];
  __shared__ float s_mu, s_rs;
  int t = threadIdx.x;
  float tv = t_in[0];
  if (t < 64){
    int i = t & 31;
    float fr = __expf((float)i * (-9.210340371976184f/31.f));
    float a = tv * fr;
    emb[t] = (t < 32) ? sinf(a) : cosf(a);
  }
  __syncthreads();
  {
    float z = b1[t];
    for (int i=0;i<64;i++) z += emb[i]*w1[i*128+t];
    h1[t] = silu_f(z);
  }
  __syncthreads();
  float tp = 0.f;
  if (t < 64){
    tp = b2[t];
    for (int j=0;j<128;j++) tp += h1[j]*w2[j*64+t];
  }
  red[t] = (t<64)? tp : 0.f;
  __syncthreads();
  for (int st=64;st;st>>=1){ if(t<st) red[t]+=red[t+st]; __syncthreads(); }
  if (t==0) s_mu = red[0]/64.f;
  __syncthreads();
  float d = tp - s_mu;
  red[t] = (t<64)? d*d : 0.f;
  __syncthreads();
  for (int st=64;st;st>>=1){ if(t<st) red[t]+=red[t+st]; __syncthreads(); }
  if (t==0) s_rs = rsqrtf(red[0]/64.f + 1e-5f);
  __syncthreads();
  if (t<64) temb[t] = g[t]*(d*s_rs) + b[t];
}

// ------- merged node encoder (ligand rows < Nl, protein rows >= Nl) fused with s0 -------
__global__ void k_encall(const float* __restrict__ pf, const float* __restrict__ lf, int Nl,
    const float* __restrict__ pw1, const float* __restrict__ pb1,
    const float* __restrict__ pg,  const float* __restrict__ pbb,
    const float* __restrict__ pw2, const float* __restrict__ pb2,
    const float* __restrict__ lw1, const float* __restrict__ lb1,
    const float* __restrict__ lg,  const float* __restrict__ lbb,
    const float* __restrict__ lw2, const float* __restrict__ lb2,
    const float* __restrict__ spw, const float* __restrict__ spb,
    const float* __restrict__ embw, float* __restrict__ s){
  __shared__ float sx[96], sh[128], red[128], vout[48], c48[48];
  __shared__ float s_mu, s_rs;
  int row = blockIdx.x, t = threadIdx.x;
  bool lig = row < Nl;
  int in_dim = lig ? 52 : 96;
  const float* x  = lig ? (lf + (size_t)row*52) : (pf + (size_t)(row-Nl)*96);
  const float* w1 = lig ? lw1 : pw1;
  const float* b1 = lig ? lb1 : pb1;
  const float* g  = lig ? lg  : pg;
  const float* bb = lig ? lbb : pbb;
  const float* w2 = lig ? lw2 : pw2;
  const float* b2 = lig ? lb2 : pb2;
  for (int i=t;i<in_dim;i+=128) sx[i] = x[i];
  __syncthreads();
  float z = b1[t];
  for (int i=0;i<in_dim;i++) z += sx[i]*w1[i*128+t];
  red[t]=z; __syncthreads();
  for (int st=64;st;st>>=1){ if(t<st) red[t]+=red[t+st]; __syncthreads(); }
  if(!t) s_mu = red[0]/128.f;
  __syncthreads();
  float d = z - s_mu;
  red[t]=d*d; __syncthreads();
  for (int st=64;st;st>>=1){ if(t<st) red[t]+=red[t+st]; __syncthreads(); }
  if(!t) s_rs = rsqrtf(red[0]/128.f+1e-5f);
  __syncthreads();
  float h = g[t]*(d*s_rs)+bb[t];
  sh[t] = silu_f(h);
  __syncthreads();
  if (t<48){
    float o = b2[t];
    for (int j=0;j<128;j++) o += sh[j]*w2[j*48+t];
    vout[t] = o;
  }
  __syncthreads();
  if (t<48){
    float c = spb[t];
    for (int i=0;i<48;i++) c += vout[i]*spw[i*48+t];
    c48[t] = c;
  }
  __syncthreads();
  if (t<48){
    float v = 0.f;
    for (int i=0;i<48;i++) v += c48[i]*embw[i*48+t];
    s[(size_t)row*48+t] = v*I48;
  }
}

// ---------------- per-edge: dist -> ef(32); also degree atomics ----------------
__global__ void k_edge(const float* __restrict__ lc, const float* __restrict__ pc,
                       const int* __restrict__ src, const int* __restrict__ dst,
                       const float* __restrict__ temb,
                       const float* __restrict__ w1, const float* __restrict__ b1,
                       const float* __restrict__ w2, const float* __restrict__ b2,
                       float* __restrict__ ef, float* __restrict__ degf,
                       int E, int Nl){
  __shared__ float sh_h[2][32];
  int t = threadIdx.x, sub = t>>5, j = t&31;
  int e = blockIdx.x*2 + sub;
  if (e < E){
    int s_ = src[e], d_ = dst[e];
    float vx = lc[(size_t)s_*3+0]-pc[(size_t)d_*6+0];
    float vy = lc[(size_t)s_*3+1]-pc[(size_t)d_*6+1];
    float vz = lc[(size_t)s_*3+2]-pc[(size_t)d_*6+2];
    float dist = sqrtf(vx*vx+vy*vy+vz*vz+1e-12f);
    float h = b1[j] + dist*w1[j];
    for (int a=0;a<64;a++) h += temb[a]*w1[(a+1)*32+j];
    sh_h[sub][j] = silu_f(h);
  }
  __syncthreads();
  if (e < E){
    float o = b2[j];
    for (int a=0;a<32;a++) o += sh_h[sub][a]*w2[a*32+j];
    ef[(size_t)e*32+j] = o;
    if (j==0) atomicAdd(&degf[Nl + dst[e]], 1.f);
  }
}

// ------- pack v2: transpose-through-LDS, fully coalesced half8 stores -------
__global__ __launch_bounds__(256) void k_pack2(
    const float* __restrict__ w3, const float* __restrict__ b3,
    const float* __restrict__ w1, const float* __restrict__ w2,
    _Float16* __restrict__ wbh,
    _Float16* __restrict__ w1p, _Float16* __restrict__ w2p, int L){
  const int t = threadIdx.x;
  const int b = blockIdx.x;
  const int mainN = L*48;
  if (b < mainN){
    __shared__ float sw3[128][49];
    const int l = b / 48, i = b - (b/48)*48;
    const float* srow = w3 + (size_t)l*128*11520 + (size_t)i*48;
    for (int v = t; v < 1536; v += 256){
      int kk = v / 12, og = v - kk*12;
      float4 f = *(const float4*)(srow + (size_t)kk*11520 + og*4);
      sw3[kk][og*4+0] = f.x; sw3[kk][og*4+1] = f.y;
      sw3[kk][og*4+2] = f.z; sw3[kk][og*4+3] = f.w;
    }
    __syncthreads();
    _Float16* dst0 = wbh + ((size_t)(l*NKB + i*4))*1536;
    for (int v = t; v < 768; v += 256){
      int kb = v / 192, rem = v - kb*192;
      int nt = rem >> 6, lane = rem & 63;
      int kkb = kb*32 + ((lane>>4)<<3);
      int o = nt*16 + (lane & 15);
      half8 hv;
      #pragma unroll
      for (int j=0;j<8;j++) hv[j] = (_Float16)sw3[kkb + j][o];
      *(half8*)(dst0 + ((size_t)(kb*3 + nt))*512 + lane*8) = hv;
    }
    return;
  }
  if (b < mainN + L){
    const int l = b - mainN;
    _Float16* dst0 = wbh + ((size_t)l*NKB + 192)*1536;
    const float* b3l = b3 + (size_t)l*11520;
    for (int v = t; v < 384; v += 256){
      int kb = v / 192, rem = v - kb*192;
      int nt = rem >> 6, lane = rem & 63;
      int iib = kb*32 + ((lane>>4)<<3);
      int o = nt*16 + (lane & 15);
      half8 hv;
      #pragma unroll
      for (int j=0;j<8;j++){
        int ii = iib + j;
        hv[j] = (ii < 48) ? (_Float16)b3l[ii*48 + o] : (_Float16)0.f;
      }
      *(half8*)(dst0 + ((size_t)(kb*3 + nt))*512 + lane*8) = hv;
    }
    return;
  }
  if (b < mainN + 2*L){
    const int l = b - mainN - L;
    for (int v = t; v < 512; v += 256){
      int nt = v >> 6, lane = v & 63;
      int kbse = (lane>>4)<<3;
      int o = nt*16 + (lane & 15);
      half8 hv;
      #pragma unroll
      for (int j=0;j<8;j++) hv[j] = (_Float16)w1[((size_t)l*32 + kbse + j)*128 + o];
      *(half8*)(w1p + (((size_t)l*8 + nt)*64 + lane)*8) = hv;
    }
    return;
  }
  {
    const int l = b - mainN - 2*L;
    for (int v = t; v < 2048; v += 256){
      int kb = v >> 9, rem = v & 511;
      int nt = rem >> 6, lane = rem & 63;
      int kbse = kb*32 + ((lane>>4)<<3);
      int o = nt*16 + (lane & 15);
      half8 hv;
      #pragma unroll
      for (int j=0;j<8;j++) hv[j] = (_Float16)w2[((size_t)l*128 + kbse + j)*128 + o];
      *(half8*)(w2p + (((size_t)(l*4 + kb)*8 + nt)*64 + lane)*8) = hv;
    }
    return;
  }
}

// ---------------- edge MLP via MFMA: 64 edges x 1 layer per block ----------------
__global__ __launch_bounds__(256) void k_mlp2(
    const float* __restrict__ ef,
    const _Float16* __restrict__ w1p, const float* __restrict__ b1a,
    const _Float16* __restrict__ w2p, const float* __restrict__ b2a,
    _Float16* __restrict__ m2h, int E){
  __shared__ __align__(16) _Float16 sef[64][40];
  __shared__ __align__(16) _Float16 shh[64][136];
  __shared__ float sb1[128], sb2[128];
  const int t = threadIdx.x, lane = t & 63, w = t >> 6;
  const int e0 = blockIdx.x * 64;
  const int l  = blockIdx.y;
  const _Float16* w1l = w1p + (size_t)l*4096;
  const _Float16* w2l = w2p + (size_t)l*16384;
  if (t < 128) sb1[t] = b1a[l*128 + t];
  else         sb2[t-128] = b2a[l*128 + (t-128)];
  {
    int row = t >> 2, g = t & 3;
    const float* p = ef + ((size_t)(e0+row))*32 + g*8;
    float4 p0 = *(const float4*)p, p1 = *(const float4*)(p+4);
    half8 hv;
    hv[0]=(_Float16)p0.x; hv[1]=(_Float16)p0.y; hv[2]=(_Float16)p0.z; hv[3]=(_Float16)p0.w;
    hv[4]=(_Float16)p1.x; hv[5]=(_Float16)p1.y; hv[6]=(_Float16)p1.z; hv[7]=(_Float16)p1.w;
    *(half8*)&sef[row][g*8] = hv;
  }
  __syncthreads();
  const int m = lane & 15, quad = lane >> 4;
  const int r = w*16 + m;
  half8 a1 = *(const half8*)&sef[r][quad*8];
  f32x4 acc1[8];
  #pragma unroll
  for (int nt=0; nt<8; nt++){
    half8 b = *(const half8*)(w1l + (nt*64 + lane)*8);
    f32x4 z = {0.f,0.f,0.f,0.f};
    acc1[nt] = __builtin_amdgcn_mfma_f32_16x16x32_f16(a1, b, z, 0,0,0);
  }
  #pragma unroll
  for (int nt=0; nt<8; nt++){
    float bv = sb1[nt*16 + m];
    #pragma unroll
    for (int rr=0; rr<4; rr++)
      shh[w*16 + quad*4 + rr][nt*16 + m] = (_Float16)silu_f(acc1[nt][rr] + bv);
  }
  __syncthreads();
  f32x4 acc2[8];
  #pragma unroll
  for (int nt=0;nt<8;nt++) acc2[nt] = (f32x4){0.f,0.f,0.f,0.f};
  #pragma unroll
  for (int kb=0; kb<4; kb++){
    half8 a2 = *(const half8*)&shh[r][kb*32 + quad*8];
    #pragma unroll
    for (int nt=0; nt<8; nt++){
      half8 b = *(const half8*)(w2l + ((size_t)(kb*8+nt)*64 + lane)*8);
      acc2[nt] = __builtin_amdgcn_mfma_f32_16x16x32_f16(a2, b, acc2[nt], 0,0,0);
    }
  }
  __syncthreads();
  #pragma unroll
  for (int nt=0; nt<8; nt++){
    float bv = sb2[nt*16 + m];
    #pragma unroll
    for (int rr=0; rr<4; rr++)
      shh[w*16 + quad*4 + rr][nt*16 + m] = (_Float16)silu_f(acc2[nt][rr] + bv);
  }
  __syncthreads();
  for (int q = t; q < 64*16; q += 256){
    int row = q >> 4, c = q & 15;
    half8 hv = *(const half8*)&shh[row][c*8];
    *(half8*)(m2h + ((size_t)l*E + e0 + row)*128 + c*8) = hv;
  }
}

// ==================== verbatim phase bodies (proven correct in fused vehicle, r9) ====

__device__ __forceinline__ void msg_body(int xe, int by,
    const _Float16* __restrict__ m2h, const float* __restrict__ s,
    const float* __restrict__ a_s, const float* __restrict__ bnlp,
    const float* __restrict__ gp, const float* __restrict__ bp, int apply, int N,
    const _Float16* __restrict__ wbh,
    const int* __restrict__ src, const int* __restrict__ dst,
    float* __restrict__ Sacc, int Nl){
  __shared__ __align__(16) _Float16 sB[2][KCH*1536];   // 2 x 12 KiB
  __shared__ __align__(16) _Float16 sseq[64][72];      // 9.2 KiB
  __shared__ int sdst[64];
  __shared__ float ksc[48], kbs[48];
  const int t = threadIdx.x, lane = t & 63, w = t >> 6;
  const int e0 = xe * 64;
  const int kb0 = by*32;
  const int kb1 = (by==KSPL-1) ? NKB : kb0+32;

  if (t < 48){
    if (apply){
      float su = bnlp[t], sq = bnlp[48+t];
      float mu  = su/(float)N;
      float var = sq/(float)N - mu*mu;
      float r = rsqrtf(var + 1e-5f);
      float sc = gp[t]*r;
      ksc[t] = sc; kbs[t] = bp[t] - mu*sc;
    } else { ksc[t]=0.f; kbs[t]=0.f; }
  }
  if (t < 64) sdst[t] = dst[e0+t];
  __syncthreads();

  for (int q = t; q < 64*9; q += 256){
    int e = q/9, g = q - e*9;
    half8 hv = {};
    if (g < 6){
      size_t base = (size_t)src[e0+e]*48 + g*8;
      const float* sp = s + base;
      if (apply){
        const float* ap = a_s + base;
        #pragma unroll
        for (int j=0;j<8;j++){
          int o = g*8+j;
          hv[j] = (_Float16)(sp[j] + ap[j]*ksc[o] + kbs[o]);
        }
      } else {
        #pragma unroll
        for (int j=0;j<8;j++) hv[j] = (_Float16)sp[j];
      }
    }
    *(half8*)&sseq[e][g*8] = hv;
  }

  const int m = lane & 15, quad = lane >> 4;
  const int r0 = w*16 + m;

  half8 f0[4];
  {
    const _Float16* base0 = m2h + (size_t)(e0+r0)*128 + quad*8;
    #pragma unroll
    for (int sub=0; sub<4; sub++) f0[sub] = *(const half8*)(base0 + sub*32);
  }

  auto stage = [&](int c){
    int kbase = kb0 + c*KCH;
    int nk = kb1 - kbase; if (nk > KCH) nk = KCH;
    int bytes = nk*3072;
    const char* g = (const char*)wbh + (size_t)kbase*3072;
    char* lb = (char*)sB[c&1];
    for (int off = w*1024; off < bytes; off += 4096){
      __builtin_amdgcn_global_load_lds(
        (const __attribute__((address_space(1))) void*)(g + off + (size_t)lane*16),
        (__attribute__((address_space(3))) void*)(lb + off), 16, 0, 0);
    }
  };
  stage(0);

  f32x4 acc0={0.f,0.f,0.f,0.f}, acc1={0.f,0.f,0.f,0.f}, acc2={0.f,0.f,0.f,0.f};

  const int nch = (kb1-kb0+KCH-1)/KCH;
  for (int c = 0; c < nch; c++){
    __syncthreads();              // drains stage(c)
    if (c+1 < nch) stage(c+1);    // prefetch next chunk into other buffer
    int kbase = kb0 + c*KCH;
    int kbn = kb1 - kbase; if (kbn > KCH) kbn = KCH;
    const _Float16* bb = sB[c&1];
    if (kbn == KCH && kbase < 192){
      int i = kbase >> 2;
      _Float16 sv0 = sseq[r0][i];
      half8 s0v = {sv0,sv0,sv0,sv0,sv0,sv0,sv0,sv0};
      #pragma unroll
      for (int kk = 0; kk < KCH; kk++){
        half8 a0 = f0[kk] * s0v;  // v_pk_mul_f16 x4
        const _Float16* bk = bb + kk*1536 + lane*8;
        half8 b0 = *(const half8*)(bk);
        half8 b1 = *(const half8*)(bk + 512);
        half8 b2 = *(const half8*)(bk + 1024);
        acc0 = __builtin_amdgcn_mfma_f32_16x16x32_f16(a0, b0, acc0, 0, 0, 0);
        acc1 = __builtin_amdgcn_mfma_f32_16x16x32_f16(a0, b1, acc1, 0, 0, 0);
        acc2 = __builtin_amdgcn_mfma_f32_16x16x32_f16(a0, b2, acc2, 0, 0, 0);
      }
    } else {
      for (int kk = 0; kk < kbn; kk++){
        int kblk = kbase + kk;
        int ib = ((kblk-192) << 5) + quad*8;
        half8 a0 = *(const half8*)&sseq[r0][ib];
        const _Float16* bk = bb + kk*1536 + lane*8;
        half8 b0 = *(const half8*)(bk);
        half8 b1 = *(const half8*)(bk + 512);
        half8 b2 = *(const half8*)(bk + 1024);
        acc0 = __builtin_amdgcn_mfma_f32_16x16x32_f16(a0, b0, acc0, 0, 0, 0);
        acc1 = __builtin_amdgcn_mfma_f32_16x16x32_f16(a0, b1, acc1, 0, 0, 0);
        acc2 = __builtin_amdgcn_mfma_f32_16x16x32_f16(a0, b2, acc2, 0, 0, 0);
      }
    }
  }
  #pragma unroll
  for (int r = 0; r < 4; r++){
    int el0 = w*16 + quad*4 + r;
    float* p0 = Sacc + (size_t)(Nl + sdst[el0])*48 + m;
    atomicAdd(p0 +  0, acc0[r]*I48);
    atomicAdd(p0 + 16, acc1[r]*I48);
    atomicAdd(p0 + 32, acc2[r]*I48);
  }
}

__device__ __forceinline__ void node_body(int nb, float* __restrict__ Sacc,
                       const float* __restrict__ degf,
                       float* __restrict__ s, const float* __restrict__ siw,
                       float* __restrict__ a_s,
                       const float* __restrict__ bnlp, const float* __restrict__ gp,
                       const float* __restrict__ bp, int apply,
                       float* __restrict__ bnl, int N){
  __shared__ float sh_s[16][48];
  __shared__ float sw[2304];
  __shared__ float csum[48], csq[48];
  __shared__ float ksc[48], kbs[48];
  int t = threadIdx.x;
  int n0 = nb*16;
  if (t < 48){
    if (apply){
      float su = bnlp[t], sq = bnlp[48+t];
      float mu  = su/(float)N;
      float var = sq/(float)N - mu*mu;
      float r = rsqrtf(var + 1e-5f);
      float sc = gp[t]*r;
      ksc[t] = sc; kbs[t] = bp[t] - mu*sc;
    } else { ksc[t]=0.f; kbs[t]=0.f; }
    csum[t]=0.f; csq[t]=0.f;
  }
  for (int q=t;q<2304;q+=256) sw[q] = siw[q];
  __syncthreads();
  for (int q=t;q<768;q+=256){
    int nl=q/48, o=q-nl*48;
    size_t idx = (size_t)(n0+nl)*48+o;
    float v = s[idx];
    if (apply){
      v += a_s[idx]*ksc[o] + kbs[o];
      s[idx] = v;            // persist T_l
    }
    sh_s[nl][o] = v;
  }
  __syncthreads();
  int nl = t>>4;
  int ob = (t&15)*3;
  int n = n0+nl;
  float dg = degf[n]; if (dg < 1.f) dg = 1.f;
  float inv = 1.f/dg;
  #pragma unroll
  for (int j=0;j<3;j++){
    int o = ob+j;
    size_t idx = (size_t)n*48+o;
    float acc = 0.f;
    for (int i=0;i<48;i++) acc += sh_s[nl][i]*sw[i*48+o];
    float a = Sacc[idx]*inv + acc*I48;
    Sacc[idx] = 0.f;         // ready for next layer
    a_s[idx] = a;
    atomicAdd(&csum[o], a);
    atomicAdd(&csq[o], a*a);
  }
  __syncthreads();
  if (t<96) atomicAdd(&bnl[t], (t<48) ? csum[t] : csq[t-48]);
}

__device__ __forceinline__ void out_body(int n, const float* __restrict__ s,
                       const float* __restrict__ a_s,
                       const float* __restrict__ bnlp, const float* __restrict__ gp,
                       const float* __restrict__ bp, int N,
                       const float* __restrict__ ows, float* __restrict__ out){
  __shared__ float sh_s[48];
  __shared__ float ksc[48], kbs[48];
  int t = threadIdx.x;
  if (t < 48){
    float su = bnlp[t], sq = bnlp[48+t];
    float mu  = su/(float)N;
    float var = sq/(float)N - mu*mu;
    float r = rsqrtf(var + 1e-5f);
    float sc = gp[t]*r;
    ksc[t] = sc; kbs[t] = bp[t] - mu*sc;
  }
  __syncthreads();
  if (t<48){
    size_t idx = (size_t)n*48+t;
    sh_s[t] = s[idx] + a_s[idx]*ksc[t] + kbs[t];
  }
  __syncthreads();
  float acc = 0.f;
  for (int i=0;i<48;i++) acc += sh_s[i]*ows[i*256+t];
  out[(size_t)n*259 + 3 + t] = acc*I48;
  if (t<3) out[(size_t)n*259 + t] = 0.f;
  __syncthreads();   // before next grid-stride iteration reuses sh_s
}

// ======== fused layer loop (DIY grid barrier): 6x(msg, node) + out ========
__global__ __launch_bounds__(256, 3) void k_loop(
    const _Float16* __restrict__ m2h, float* __restrict__ s,
    float* __restrict__ a_s, float* __restrict__ Sacc, float* __restrict__ bnb,
    const float* __restrict__ bn_gs, const float* __restrict__ bn_bs,
    const _Float16* __restrict__ wbh,
    const int* __restrict__ src, const int* __restrict__ dst,
    const float* __restrict__ degf, const float* __restrict__ si_ws,
    const float* __restrict__ ows, float* __restrict__ out,
    int* __restrict__ bars,
    int E, int N, int Nl, int L){
  const int bid = blockIdx.x, nblk = gridDim.x;
  const int NXB = E/64;
  const int nnode = N/16;
  int slot = 0;
  for (int l = 0; l < L; l++){
    const float* bnlp = (l>0) ? (bnb + (l-1)*96) : bnb;
    const float* gp   = (l>0) ? (bn_gs + (l-1)*48) : bn_gs;
    const float* bp   = (l>0) ? (bn_bs + (l-1)*48) : bn_bs;
    int apply = (l>0) ? 1 : 0;
    msg_body(bid % NXB, bid / NXB, m2h + (size_t)l*E*128, s, a_s, bnlp, gp, bp,
             apply, N, wbh + (size_t)l*NKB*1536, src, dst, Sacc, Nl);
    gsync(bars, slot++, nblk);
    if (bid < nnode)
      node_body(bid, Sacc, degf, s, si_ws + (size_t)l*2304, a_s,
                bnlp, gp, bp, apply, bnb + l*96, N);
    gsync(bars, slot++, nblk);
  }
  for (int n = bid; n < Nl; n += nblk)
    out_body(n, s, a_s, bnb + (L-1)*96, bn_gs + (L-1)*48, bn_bs + (L-1)*48,
             N, ows, out);
}

// ======== standalone fallbacks: byte-identical to the passing round-6 kernels ========
__global__ __launch_bounds__(256) void k_msg7(
    const _Float16* __restrict__ m2h, const float* __restrict__ s,
    const float* __restrict__ a_s, const float* __restrict__ bnlp,
    const float* __restrict__ gp, const float* __restrict__ bp, int apply, int N,
    const _Float16* __restrict__ wbh,
    const int* __restrict__ src, const int* __restrict__ dst,
    float* __restrict__ Sacc, int Nl){
  msg_body(blockIdx.x, blockIdx.y, m2h, s, a_s, bnlp, gp, bp, apply, N,
           wbh, src, dst, Sacc, Nl);
}

__global__ __launch_bounds__(256) void k_node3(float* __restrict__ Sacc,
                       const float* __restrict__ degf,
                       float* __restrict__ s, const float* __restrict__ siw,
                       float* __restrict__ a_s,
                       const float* __restrict__ bnlp, const float* __restrict__ gp,
                       const float* __restrict__ bp, int apply,
                       float* __restrict__ bnl, int N){
  node_body(blockIdx.x, Sacc, degf, s, siw, a_s, bnlp, gp, bp, apply, bnl, N);
}

__global__ void k_out2(const float* __restrict__ s, const float* __restrict__ a_s,
                       const float* __restrict__ bnlp, const float* __restrict__ gp,
                       const float* __restrict__ bp, int N,
                       const float* __restrict__ ows, float* __restrict__ out){
  out_body(blockIdx.x, s, a_s, bnlp, gp, bp, N, ows, out);
}

extern "C" void kernel_launch(void* const* d_in, const int* in_sizes, int n_in,
                              void* d_out, int out_size, void* d_ws, size_t ws_size,
                              hipStream_t stream){
  const float* protein_coords   = (const float*)d_in[0];
  const float* protein_features = (const float*)d_in[1];
  const float* ligand_coords    = (const float*)d_in[2];
  const float* ligand_features  = (const float*)d_in[3];
  const float* t_in    = (const float*)d_in[4];
  const float* te_w1   = (const float*)d_in[5];
  const float* te_b1   = (const float*)d_in[6];
  const float* te_w2   = (const float*)d_in[7];
  const float* te_b2   = (const float*)d_in[8];
  const float* te_ln_g = (const float*)d_in[9];
  const float* te_ln_b = (const float*)d_in[10];
  const float* pe_w1   = (const float*)d_in[11];
  const float* pe_b1   = (const float*)d_in[12];
  const float* pe_ln_g = (const float*)d_in[13];
  const float* pe_ln_b = (const float*)d_in[14];
  const float* pe_w2   = (const float*)d_in[15];
  const float* pe_b2   = (const float*)d_in[16];
  const float* le_w1   = (const float*)d_in[17];
  const float* le_b1   = (const float*)d_in[18];
  const float* le_ln_g = (const float*)d_in[19];
  const float* le_ln_b = (const float*)d_in[20];
  const float* le_w2   = (const float*)d_in[21];
  const float* le_b2   = (const float*)d_in[22];
  const float* sp_w    = (const float*)d_in[23];
  const float* sp_b    = (const float*)d_in[24];
  const float* emb_w   = (const float*)d_in[25];
  const float* ee_w1   = (const float*)d_in[26];
  const float* ee_b1   = (const float*)d_in[27];
  const float* ee_w2   = (const float*)d_in[28];
  const float* ee_b2   = (const float*)d_in[29];
  const float* conv_w1 = (const float*)d_in[30];
  const float* conv_b1 = (const float*)d_in[31];
  const float* conv_w2 = (const float*)d_in[32];
  const float* conv_b2 = (const float*)d_in[33];
  const float* conv_w3 = (const float*)d_in[34];
  const float* conv_b3 = (const float*)d_in[35];
  const float* bn_gs   = (const float*)d_in[36];
  const float* bn_bs   = (const float*)d_in[37];
  const float* si_ws   = (const float*)d_in[40];
  const float* out_ws  = (const float*)d_in[43];
  const int* edge_src  = (const int*)d_in[45];
  const int* edge_dst  = (const int*)d_in[46];

  int Np = in_sizes[0]/6;
  int Nl = in_sizes[2]/3;
  int E  = in_sizes[45];
  int N  = Nl+Np;
  int L  = in_sizes[36]/48;

  float* W = (float*)d_ws;
  size_t off = 0;
  auto alloc = [&](size_t n)->float*{ float* p = W+off; off += (n+63)&~(size_t)63; return p; };
  // degf, Sacc, bnb, bars contiguous -> single startup memset
  float* degf  = alloc(N);
  float* Sacc  = alloc((size_t)N*48);
  float* bnb   = alloc((size_t)L*96);
  int*   bars  = (int*)alloc(64);           // grid-barrier slots (12 used)
  float* temb  = alloc(64);
  float* sbuf  = alloc((size_t)N*48);
  float* ef    = alloc((size_t)E*32);
  float* a_s   = alloc((size_t)N*48);
  _Float16* m2h = (_Float16*)alloc((size_t)L*E*128/2 + 64);
  _Float16* wbh = (_Float16*)alloc((size_t)L*NKB*1536/2 + 64);
  _Float16* w1p = (_Float16*)alloc((size_t)L*4096/2 + 64);
  _Float16* w2p = (_Float16*)alloc((size_t)L*16384/2 + 64);

  hipMemsetAsync(degf, 0, ((size_t)N + (size_t)N*48 + (size_t)L*96 + 64 + 192)*sizeof(float), stream);
  k_pack2<<<L*51,256,0,stream>>>(conv_w3, conv_b3, conv_w1, conv_w2, wbh, w1p, w2p, L);
  k_temb<<<1,128,0,stream>>>(t_in, te_w1, te_b1, te_w2, te_b2, te_ln_g, te_ln_b, temb);
  k_encall<<<N,128,0,stream>>>(protein_features, ligand_features, Nl,
                               pe_w1, pe_b1, pe_ln_g, pe_ln_b, pe_w2, pe_b2,
                               le_w1, le_b1, le_ln_g, le_ln_b, le_w2, le_b2,
                               sp_w, sp_b, emb_w, sbuf);
  k_edge<<<(E+1)/2,64,0,stream>>>(ligand_coords, protein_coords, edge_src, edge_dst, temb,
                                  ee_w1, ee_b1, ee_w2, ee_b2, ef, degf, E, Nl);
  dim3 mlpg(E/64, L);
  k_mlp2<<<mlpg,256,0,stream>>>(ef, w1p, conv_b1, w2p, conv_b2, m2h, E);

  int NXB  = E/64;
  int nblk = NXB*KSPL;   // 768 = 256 CU x 3 blocks (LDS 47KiB, VGPR 84 -> 3/CU)
  bool coop = (nblk == 768) && (E % 64 == 0) && (N % 16 == 0);

  if (coop){
    k_loop<<<nblk,256,0,stream>>>(m2h, sbuf, a_s, Sacc, bnb, bn_gs, bn_bs, wbh,
                                  edge_src, edge_dst, degf, si_ws, out_ws,
                                  (float*)d_out, bars, E, N, Nl, L);
  } else {
    dim3 mgrid(NXB, KSPL);
    for (int l=0;l<L;l++){
      const float* bnlp = (l>0) ? (bnb + (l-1)*96) : bnb;
      const float* gp   = (l>0) ? (bn_gs + (l-1)*48) : bn_gs;
      const float* bp   = (l>0) ? (bn_bs + (l-1)*48) : bn_bs;
      int apply = (l>0) ? 1 : 0;
      k_msg7<<<mgrid,256,0,stream>>>(m2h + (size_t)l*E*128, sbuf, a_s, bnlp, gp, bp, apply, N,
                                     wbh + (size_t)l*NKB*1536, edge_src, edge_dst, Sacc, Nl);
      k_node3<<<N/16,256,0,stream>>>(Sacc, degf, sbuf, si_ws + (size_t)l*2304, a_s,
                                     bnlp, gp, bp, apply, bnb + l*96, N);
    }
    k_out2<<<Nl,256,0,stream>>>(sbuf, a_s, bnb + (L-1)*96, bn_gs + (L-1)*48, bn_bs + (L-1)*48,
                                N, out_ws, (float*)d_out);
  }
}

// Round 11
// 443.770 us; speedup vs baseline: 6.2458x; 6.2458x over previous
//
#include <hip/hip_runtime.h>
#include <hip/hip_bf16.h>
#include <math.h>

#define I48 0.14433756729740643f  // 1/sqrt(48)
#define NKB 194                   // 6144 W rows + 64 bias rows, /32
#define KCH 4                     // kblks per LDS chunk (12 KiB fp16)
#define KSPL 6                    // K-split across blockIdx.y (proven optimum: 3 blocks/CU)

typedef __attribute__((ext_vector_type(8))) _Float16 half8;
typedef __attribute__((ext_vector_type(4))) float f32x4;

__device__ __forceinline__ float silu_f(float x){ return x / (1.f + __expf(-x)); }

// ------- merged node encoder (rows < N) + time embedding (row == N, verbatim temb body) -------
__global__ void k_encall(const float* __restrict__ pf, const float* __restrict__ lf, int Nl,
    const float* __restrict__ pw1, const float* __restrict__ pb1,
    const float* __restrict__ pg,  const float* __restrict__ pbb,
    const float* __restrict__ pw2, const float* __restrict__ pb2,
    const float* __restrict__ lw1, const float* __restrict__ lb1,
    const float* __restrict__ lg,  const float* __restrict__ lbb,
    const float* __restrict__ lw2, const float* __restrict__ lb2,
    const float* __restrict__ spw, const float* __restrict__ spb,
    const float* __restrict__ embw, float* __restrict__ s,
    int N,
    const float* __restrict__ t_in,
    const float* __restrict__ tw1, const float* __restrict__ tb1,
    const float* __restrict__ tw2, const float* __restrict__ tb2,
    const float* __restrict__ tg,  const float* __restrict__ tbb,
    float* __restrict__ temb){
  __shared__ float sx[96], sh[128], red[128], vout[48], c48[48];
  __shared__ float s_mu, s_rs;
  int row = blockIdx.x, t = threadIdx.x;
  if (row == N){
    // ---- time embedding: verbatim k_temb body (128 threads), emb->sx, h1->sh ----
    float tv = t_in[0];
    if (t < 64){
      int i = t & 31;
      float fr = __expf((float)i * (-9.210340371976184f/31.f));
      float a = tv * fr;
      sx[t] = (t < 32) ? sinf(a) : cosf(a);
    }
    __syncthreads();
    {
      float z = tb1[t];
      for (int i=0;i<64;i++) z += sx[i]*tw1[i*128+t];
      sh[t] = silu_f(z);
    }
    __syncthreads();
    float tp = 0.f;
    if (t < 64){
      tp = tb2[t];
      for (int j=0;j<128;j++) tp += sh[j]*tw2[j*64+t];
    }
    red[t] = (t<64)? tp : 0.f;
    __syncthreads();
    for (int st=64;st;st>>=1){ if(t<st) red[t]+=red[t+st]; __syncthreads(); }
    if (t==0) s_mu = red[0]/64.f;
    __syncthreads();
    float d = tp - s_mu;
    red[t] = (t<64)? d*d : 0.f;
    __syncthreads();
    for (int st=64;st;st>>=1){ if(t<st) red[t]+=red[t+st]; __syncthreads(); }
    if (t==0) s_rs = rsqrtf(red[0]/64.f + 1e-5f);
    __syncthreads();
    if (t<64) temb[t] = tg[t]*(d*s_rs) + tbb[t];
    return;
  }
  // ---- node encoder fused with s0 (verbatim round-6 body) ----
  bool lig = row < Nl;
  int in_dim = lig ? 52 : 96;
  const float* x  = lig ? (lf + (size_t)row*52) : (pf + (size_t)(row-Nl)*96);
  const float* w1 = lig ? lw1 : pw1;
  const float* b1 = lig ? lb1 : pb1;
  const float* g  = lig ? lg  : pg;
  const float* bb = lig ? lbb : pbb;
  const float* w2 = lig ? lw2 : pw2;
  const float* b2 = lig ? lb2 : pb2;
  for (int i=t;i<in_dim;i+=128) sx[i] = x[i];
  __syncthreads();
  float z = b1[t];
  for (int i=0;i<in_dim;i++) z += sx[i]*w1[i*128+t];
  red[t]=z; __syncthreads();
  for (int st=64;st;st>>=1){ if(t<st) red[t]+=red[t+st]; __syncthreads(); }
  if(!t) s_mu = red[0]/128.f;
  __syncthreads();
  float d = z - s_mu;
  red[t]=d*d; __syncthreads();
  for (int st=64;st;st>>=1){ if(t<st) red[t]+=red[t+st]; __syncthreads(); }
  if(!t) s_rs = rsqrtf(red[0]/128.f+1e-5f);
  __syncthreads();
  float h = g[t]*(d*s_rs)+bb[t];
  sh[t] = silu_f(h);
  __syncthreads();
  if (t<48){
    float o = b2[t];
    for (int j=0;j<128;j++) o += sh[j]*w2[j*48+t];
    vout[t] = o;
  }
  __syncthreads();
  if (t<48){
    float c = spb[t];
    for (int i=0;i<48;i++) c += vout[i]*spw[i*48+t];
    c48[t] = c;
  }
  __syncthreads();
  if (t<48){
    float v = 0.f;
    for (int i=0;i<48;i++) v += c48[i]*embw[i*48+t];
    s[(size_t)row*48+t] = v*I48;
  }
}

// ---------------- per-edge: dist -> ef(32); also degree atomics ----------------
__global__ void k_edge(const float* __restrict__ lc, const float* __restrict__ pc,
                       const int* __restrict__ src, const int* __restrict__ dst,
                       const float* __restrict__ temb,
                       const float* __restrict__ w1, const float* __restrict__ b1,
                       const float* __restrict__ w2, const float* __restrict__ b2,
                       float* __restrict__ ef, float* __restrict__ degf,
                       int E, int Nl){
  __shared__ float sh_h[2][32];
  int t = threadIdx.x, sub = t>>5, j = t&31;
  int e = blockIdx.x*2 + sub;
  if (e < E){
    int s_ = src[e], d_ = dst[e];
    float vx = lc[(size_t)s_*3+0]-pc[(size_t)d_*6+0];
    float vy = lc[(size_t)s_*3+1]-pc[(size_t)d_*6+1];
    float vz = lc[(size_t)s_*3+2]-pc[(size_t)d_*6+2];
    float dist = sqrtf(vx*vx+vy*vy+vz*vz+1e-12f);
    float h = b1[j] + dist*w1[j];
    for (int a=0;a<64;a++) h += temb[a]*w1[(a+1)*32+j];
    sh_h[sub][j] = silu_f(h);
  }
  __syncthreads();
  if (e < E){
    float o = b2[j];
    for (int a=0;a<32;a++) o += sh_h[sub][a]*w2[a*32+j];
    ef[(size_t)e*32+j] = o;
    if (j==0) atomicAdd(&degf[Nl + dst[e]], 1.f);
  }
}

// ------- pack v2: transpose-through-LDS, fully coalesced half8 stores -------
__global__ __launch_bounds__(256) void k_pack2(
    const float* __restrict__ w3, const float* __restrict__ b3,
    const float* __restrict__ w1, const float* __restrict__ w2,
    _Float16* __restrict__ wbh,
    _Float16* __restrict__ w1p, _Float16* __restrict__ w2p, int L){
  const int t = threadIdx.x;
  const int b = blockIdx.x;
  const int mainN = L*48;
  if (b < mainN){
    __shared__ float sw3[128][49];
    const int l = b / 48, i = b - (b/48)*48;
    const float* srow = w3 + (size_t)l*128*11520 + (size_t)i*48;
    for (int v = t; v < 1536; v += 256){
      int kk = v / 12, og = v - kk*12;
      float4 f = *(const float4*)(srow + (size_t)kk*11520 + og*4);
      sw3[kk][og*4+0] = f.x; sw3[kk][og*4+1] = f.y;
      sw3[kk][og*4+2] = f.z; sw3[kk][og*4+3] = f.w;
    }
    __syncthreads();
    _Float16* dst0 = wbh + ((size_t)(l*NKB + i*4))*1536;
    for (int v = t; v < 768; v += 256){
      int kb = v / 192, rem = v - kb*192;
      int nt = rem >> 6, lane = rem & 63;
      int kkb = kb*32 + ((lane>>4)<<3);
      int o = nt*16 + (lane & 15);
      half8 hv;
      #pragma unroll
      for (int j=0;j<8;j++) hv[j] = (_Float16)sw3[kkb + j][o];
      *(half8*)(dst0 + ((size_t)(kb*3 + nt))*512 + lane*8) = hv;
    }
    return;
  }
  if (b < mainN + L){
    const int l = b - mainN;
    _Float16* dst0 = wbh + ((size_t)l*NKB + 192)*1536;
    const float* b3l = b3 + (size_t)l*11520;
    for (int v = t; v < 384; v += 256){
      int kb = v / 192, rem = v - kb*192;
      int nt = rem >> 6, lane = rem & 63;
      int iib = kb*32 + ((lane>>4)<<3);
      int o = nt*16 + (lane & 15);
      half8 hv;
      #pragma unroll
      for (int j=0;j<8;j++){
        int ii = iib + j;
        hv[j] = (ii < 48) ? (_Float16)b3l[ii*48 + o] : (_Float16)0.f;
      }
      *(half8*)(dst0 + ((size_t)(kb*3 + nt))*512 + lane*8) = hv;
    }
    return;
  }
  if (b < mainN + 2*L){
    const int l = b - mainN - L;
    for (int v = t; v < 512; v += 256){
      int nt = v >> 6, lane = v & 63;
      int kbse = (lane>>4)<<3;
      int o = nt*16 + (lane & 15);
      half8 hv;
      #pragma unroll
      for (int j=0;j<8;j++) hv[j] = (_Float16)w1[((size_t)l*32 + kbse + j)*128 + o];
      *(half8*)(w1p + (((size_t)l*8 + nt)*64 + lane)*8) = hv;
    }
    return;
  }
  {
    const int l = b - mainN - 2*L;
    for (int v = t; v < 2048; v += 256){
      int kb = v >> 9, rem = v & 511;
      int nt = rem >> 6, lane = rem & 63;
      int kbse = kb*32 + ((lane>>4)<<3);
      int o = nt*16 + (lane & 15);
      half8 hv;
      #pragma unroll
      for (int j=0;j<8;j++) hv[j] = (_Float16)w2[((size_t)l*128 + kbse + j)*128 + o];
      *(half8*)(w2p + (((size_t)(l*4 + kb)*8 + nt)*64 + lane)*8) = hv;
    }
    return;
  }
}

// ---------------- edge MLP via MFMA: 64 edges x 1 layer per block ----------------
__global__ __launch_bounds__(256) void k_mlp2(
    const float* __restrict__ ef,
    const _Float16* __restrict__ w1p, const float* __restrict__ b1a,
    const _Float16* __restrict__ w2p, const float* __restrict__ b2a,
    _Float16* __restrict__ m2h, int E){
  __shared__ __align__(16) _Float16 sef[64][40];
  __shared__ __align__(16) _Float16 shh[64][136];
  __shared__ float sb1[128], sb2[128];
  const int t = threadIdx.x, lane = t & 63, w = t >> 6;
  const int e0 = blockIdx.x * 64;
  const int l  = blockIdx.y;
  const _Float16* w1l = w1p + (size_t)l*4096;
  const _Float16* w2l = w2p + (size_t)l*16384;
  if (t < 128) sb1[t] = b1a[l*128 + t];
  else         sb2[t-128] = b2a[l*128 + (t-128)];
  {
    int row = t >> 2, g = t & 3;
    const float* p = ef + ((size_t)(e0+row))*32 + g*8;
    float4 p0 = *(const float4*)p, p1 = *(const float4*)(p+4);
    half8 hv;
    hv[0]=(_Float16)p0.x; hv[1]=(_Float16)p0.y; hv[2]=(_Float16)p0.z; hv[3]=(_Float16)p0.w;
    hv[4]=(_Float16)p1.x; hv[5]=(_Float16)p1.y; hv[6]=(_Float16)p1.z; hv[7]=(_Float16)p1.w;
    *(half8*)&sef[row][g*8] = hv;
  }
  __syncthreads();
  const int m = lane & 15, quad = lane >> 4;
  const int r = w*16 + m;
  half8 a1 = *(const half8*)&sef[r][quad*8];
  f32x4 acc1[8];
  #pragma unroll
  for (int nt=0; nt<8; nt++){
    half8 b = *(const half8*)(w1l + (nt*64 + lane)*8);
    f32x4 z = {0.f,0.f,0.f,0.f};
    acc1[nt] = __builtin_amdgcn_mfma_f32_16x16x32_f16(a1, b, z, 0,0,0);
  }
  #pragma unroll
  for (int nt=0; nt<8; nt++){
    float bv = sb1[nt*16 + m];
    #pragma unroll
    for (int rr=0; rr<4; rr++)
      shh[w*16 + quad*4 + rr][nt*16 + m] = (_Float16)silu_f(acc1[nt][rr] + bv);
  }
  __syncthreads();
  f32x4 acc2[8];
  #pragma unroll
  for (int nt=0;nt<8;nt++) acc2[nt] = (f32x4){0.f,0.f,0.f,0.f};
  #pragma unroll
  for (int kb=0; kb<4; kb++){
    half8 a2 = *(const half8*)&shh[r][kb*32 + quad*8];
    #pragma unroll
    for (int nt=0; nt<8; nt++){
      half8 b = *(const half8*)(w2l + ((size_t)(kb*8+nt)*64 + lane)*8);
      acc2[nt] = __builtin_amdgcn_mfma_f32_16x16x32_f16(a2, b, acc2[nt], 0,0,0);
    }
  }
  __syncthreads();
  #pragma unroll
  for (int nt=0; nt<8; nt++){
    float bv = sb2[nt*16 + m];
    #pragma unroll
    for (int rr=0; rr<4; rr++)
      shh[w*16 + quad*4 + rr][nt*16 + m] = (_Float16)silu_f(acc2[nt][rr] + bv);
  }
  __syncthreads();
  for (int q = t; q < 64*16; q += 256){
    int row = q >> 4, c = q & 15;
    half8 hv = *(const half8*)&shh[row][c*8];
    *(half8*)(m2h + ((size_t)l*E + e0 + row)*128 + c*8) = hv;
  }
}

// ---- hot kernel v7: 64 edges/block, 3 blocks/CU; deferred-BN se; A in regs; LDS for B ----
__global__ __launch_bounds__(256) void k_msg7(
    const _Float16* __restrict__ m2h, const float* __restrict__ s,
    const float* __restrict__ a_s, const float* __restrict__ bnlp,
    const float* __restrict__ gp, const float* __restrict__ bp, int apply, int N,
    const _Float16* __restrict__ wbh,
    const int* __restrict__ src, const int* __restrict__ dst,
    float* __restrict__ Sacc, int Nl){
  __shared__ __align__(16) _Float16 sB[2][KCH*1536];   // 2 x 12 KiB
  __shared__ __align__(16) _Float16 sseq[64][72];      // 9.2 KiB (se, zero-padded)
  __shared__ int sdst[64];
  __shared__ float ksc[48], kbs[48];
  const int t = threadIdx.x, lane = t & 63, w = t >> 6;
  const int e0 = blockIdx.x * 64;
  const int by = blockIdx.y;
  const int kb0 = by*32;
  const int kb1 = (by==KSPL-1) ? NKB : kb0+32;

  if (t < 48){
    if (apply){
      float su = bnlp[t], sq = bnlp[48+t];
      float mu  = su/(float)N;
      float var = sq/(float)N - mu*mu;
      float r = rsqrtf(var + 1e-5f);
      float sc = gp[t]*r;
      ksc[t] = sc; kbs[t] = bp[t] - mu*sc;
    } else { ksc[t]=0.f; kbs[t]=0.f; }
  }
  if (t < 64) sdst[t] = dst[e0+t];
  __syncthreads();

  for (int q = t; q < 64*9; q += 256){
    int e = q/9, g = q - e*9;
    half8 hv = {};
    if (g < 6){
      size_t base = (size_t)src[e0+e]*48 + g*8;
      const float* sp = s + base;
      if (apply){
        const float* ap = a_s + base;
        #pragma unroll
        for (int j=0;j<8;j++){
          int o = g*8+j;
          hv[j] = (_Float16)(sp[j] + ap[j]*ksc[o] + kbs[o]);
        }
      } else {
        #pragma unroll
        for (int j=0;j<8;j++) hv[j] = (_Float16)sp[j];
      }
    }
    *(half8*)&sseq[e][g*8] = hv;
  }

  const int m = lane & 15, quad = lane >> 4;
  const int r0 = w*16 + m;

  half8 f0[4];
  {
    const _Float16* base0 = m2h + (size_t)(e0+r0)*128 + quad*8;
    #pragma unroll
    for (int sub=0; sub<4; sub++) f0[sub] = *(const half8*)(base0 + sub*32);
  }

  auto stage = [&](int c){
    int kbase = kb0 + c*KCH;
    int nk = kb1 - kbase; if (nk > KCH) nk = KCH;
    int bytes = nk*3072;
    const char* g = (const char*)wbh + (size_t)kbase*3072;
    char* lb = (char*)sB[c&1];
    for (int off = w*1024; off < bytes; off += 4096){
      __builtin_amdgcn_global_load_lds(
        (const __attribute__((address_space(1))) void*)(g + off + (size_t)lane*16),
        (__attribute__((address_space(3))) void*)(lb + off), 16, 0, 0);
    }
  };
  stage(0);

  f32x4 acc0={0.f,0.f,0.f,0.f}, acc1={0.f,0.f,0.f,0.f}, acc2={0.f,0.f,0.f,0.f};

  const int nch = (kb1-kb0+KCH-1)/KCH;
  for (int c = 0; c < nch; c++){
    __syncthreads();              // drains stage(c)
    if (c+1 < nch) stage(c+1);    // prefetch next chunk into other buffer
    int kbase = kb0 + c*KCH;
    int kbn = kb1 - kbase; if (kbn > KCH) kbn = KCH;
    const _Float16* bb = sB[c&1];
    if (kbn == KCH && kbase < 192){
      int i = kbase >> 2;
      _Float16 sv0 = sseq[r0][i];
      half8 s0v = {sv0,sv0,sv0,sv0,sv0,sv0,sv0,sv0};
      #pragma unroll
      for (int kk = 0; kk < KCH; kk++){
        half8 a0 = f0[kk] * s0v;  // v_pk_mul_f16 x4
        const _Float16* bk = bb + kk*1536 + lane*8;
        half8 b0 = *(const half8*)(bk);
        half8 b1 = *(const half8*)(bk + 512);
        half8 b2 = *(const half8*)(bk + 1024);
        acc0 = __builtin_amdgcn_mfma_f32_16x16x32_f16(a0, b0, acc0, 0, 0, 0);
        acc1 = __builtin_amdgcn_mfma_f32_16x16x32_f16(a0, b1, acc1, 0, 0, 0);
        acc2 = __builtin_amdgcn_mfma_f32_16x16x32_f16(a0, b2, acc2, 0, 0, 0);
      }
    } else {
      for (int kk = 0; kk < kbn; kk++){
        int kblk = kbase + kk;
        int ib = ((kblk-192) << 5) + quad*8;
        half8 a0 = *(const half8*)&sseq[r0][ib];
        const _Float16* bk = bb + kk*1536 + lane*8;
        half8 b0 = *(const half8*)(bk);
        half8 b1 = *(const half8*)(bk + 512);
        half8 b2 = *(const half8*)(bk + 1024);
        acc0 = __builtin_amdgcn_mfma_f32_16x16x32_f16(a0, b0, acc0, 0, 0, 0);
        acc1 = __builtin_amdgcn_mfma_f32_16x16x32_f16(a0, b1, acc1, 0, 0, 0);
        acc2 = __builtin_amdgcn_mfma_f32_16x16x32_f16(a0, b2, acc2, 0, 0, 0);
      }
    }
  }
  #pragma unroll
  for (int r = 0; r < 4; r++){
    int el0 = w*16 + quad*4 + r;
    float* p0 = Sacc + (size_t)(Nl + sdst[el0])*48 + m;
    atomicAdd(p0 +  0, acc0[r]*I48);
    atomicAdd(p0 + 16, acc1[r]*I48);
    atomicAdd(p0 + 32, acc2[r]*I48);
  }
}

// ---- node update v3: reconstruct+persist s, self-term, a_s, BN sums, Sacc zero ----
__global__ __launch_bounds__(256) void k_node3(float* __restrict__ Sacc,
                       const float* __restrict__ degf,
                       float* __restrict__ s, const float* __restrict__ siw,
                       float* __restrict__ a_s,
                       const float* __restrict__ bnlp, const float* __restrict__ gp,
                       const float* __restrict__ bp, int apply,
                       float* __restrict__ bnl, int N){
  __shared__ float sh_s[16][48];
  __shared__ float sw[2304];
  __shared__ float csum[48], csq[48];
  __shared__ float ksc[48], kbs[48];
  int t = threadIdx.x;
  int n0 = blockIdx.x*16;
  if (t < 48){
    if (apply){
      float su = bnlp[t], sq = bnlp[48+t];
      float mu  = su/(float)N;
      float var = sq/(float)N - mu*mu;
      float r = rsqrtf(var + 1e-5f);
      float sc = gp[t]*r;
      ksc[t] = sc; kbs[t] = bp[t] - mu*sc;
    } else { ksc[t]=0.f; kbs[t]=0.f; }
    csum[t]=0.f; csq[t]=0.f;
  }
  for (int q=t;q<2304;q+=256) sw[q] = siw[q];
  __syncthreads();
  for (int q=t;q<768;q+=256){
    int nl=q/48, o=q-nl*48;
    size_t idx = (size_t)(n0+nl)*48+o;
    float v = s[idx];
    if (apply){
      v += a_s[idx]*ksc[o] + kbs[o];
      s[idx] = v;            // persist T_l
    }
    sh_s[nl][o] = v;
  }
  __syncthreads();
  int nl = t>>4;
  int ob = (t&15)*3;
  int n = n0+nl;
  float dg = degf[n]; if (dg < 1.f) dg = 1.f;
  float inv = 1.f/dg;
  #pragma unroll
  for (int j=0;j<3;j++){
    int o = ob+j;
    size_t idx = (size_t)n*48+o;
    float acc = 0.f;
    for (int i=0;i<48;i++) acc += sh_s[nl][i]*sw[i*48+o];
    float a = Sacc[idx]*inv + acc*I48;
    Sacc[idx] = 0.f;         // ready for next layer
    a_s[idx] = a;
    atomicAdd(&csum[o], a);
    atomicAdd(&csq[o], a*a);
  }
  __syncthreads();
  if (t<96) atomicAdd(&bnl[t], (t<48) ? csum[t] : csq[t-48]);
}

// ------- output with final deferred update: [0,0,0, (s_final @ out_ws)*I48] -------
__global__ void k_out2(const float* __restrict__ s, const float* __restrict__ a_s,
                       const float* __restrict__ bnlp, const float* __restrict__ gp,
                       const float* __restrict__ bp, int N,
                       const float* __restrict__ ows, float* __restrict__ out){
  __shared__ float sh_s[48];
  __shared__ float ksc[48], kbs[48];
  int n = blockIdx.x, t = threadIdx.x;
  if (t < 48){
    float su = bnlp[t], sq = bnlp[48+t];
    float mu  = su/(float)N;
    float var = sq/(float)N - mu*mu;
    float r = rsqrtf(var + 1e-5f);
    float sc = gp[t]*r;
    ksc[t] = sc; kbs[t] = bp[t] - mu*sc;
  }
  __syncthreads();
  if (t<48){
    size_t idx = (size_t)n*48+t;
    sh_s[t] = s[idx] + a_s[idx]*ksc[t] + kbs[t];
  }
  __syncthreads();
  float acc = 0.f;
  for (int i=0;i<48;i++) acc += sh_s[i]*ows[i*256+t];
  out[(size_t)n*259 + 3 + t] = acc*I48;
  if (t<3) out[(size_t)n*259 + t] = 0.f;
}

extern "C" void kernel_launch(void* const* d_in, const int* in_sizes, int n_in,
                              void* d_out, int out_size, void* d_ws, size_t ws_size,
                              hipStream_t stream){
  const float* protein_coords   = (const float*)d_in[0];
  const float* protein_features = (const float*)d_in[1];
  const float* ligand_coords    = (const float*)d_in[2];
  const float* ligand_features  = (const float*)d_in[3];
  const float* t_in    = (const float*)d_in[4];
  const float* te_w1   = (const float*)d_in[5];
  const float* te_b1   = (const float*)d_in[6];
  const float* te_w2   = (const float*)d_in[7];
  const float* te_b2   = (const float*)d_in[8];
  const float* te_ln_g = (const float*)d_in[9];
  const float* te_ln_b = (const float*)d_in[10];
  const float* pe_w1   = (const float*)d_in[11];
  const float* pe_b1   = (const float*)d_in[12];
  const float* pe_ln_g = (const float*)d_in[13];
  const float* pe_ln_b = (const float*)d_in[14];
  const float* pe_w2   = (const float*)d_in[15];
  const float* pe_b2   = (const float*)d_in[16];
  const float* le_w1   = (const float*)d_in[17];
  const float* le_b1   = (const float*)d_in[18];
  const float* le_ln_g = (const float*)d_in[19];
  const float* le_ln_b = (const float*)d_in[20];
  const float* le_w2   = (const float*)d_in[21];
  const float* le_b2   = (const float*)d_in[22];
  const float* sp_w    = (const float*)d_in[23];
  const float* sp_b    = (const float*)d_in[24];
  const float* emb_w   = (const float*)d_in[25];
  const float* ee_w1   = (const float*)d_in[26];
  const float* ee_b1   = (const float*)d_in[27];
  const float* ee_w2   = (const float*)d_in[28];
  const float* ee_b2   = (const float*)d_in[29];
  const float* conv_w1 = (const float*)d_in[30];
  const float* conv_b1 = (const float*)d_in[31];
  const float* conv_w2 = (const float*)d_in[32];
  const float* conv_b2 = (const float*)d_in[33];
  const float* conv_w3 = (const float*)d_in[34];
  const float* conv_b3 = (const float*)d_in[35];
  const float* bn_gs   = (const float*)d_in[36];
  const float* bn_bs   = (const float*)d_in[37];
  const float* si_ws   = (const float*)d_in[40];
  const float* out_ws  = (const float*)d_in[43];
  const int* edge_src  = (const int*)d_in[45];
  const int* edge_dst  = (const int*)d_in[46];

  int Np = in_sizes[0]/6;
  int Nl = in_sizes[2]/3;
  int E  = in_sizes[45];
  int N  = Nl+Np;
  int L  = in_sizes[36]/48;

  float* W = (float*)d_ws;
  size_t off = 0;
  auto alloc = [&](size_t n)->float*{ float* p = W+off; off += (n+63)&~(size_t)63; return p; };
  // degf, Sacc, bnb contiguous -> single startup memset
  float* degf  = alloc(N);
  float* Sacc  = alloc((size_t)N*48);
  float* bnb   = alloc((size_t)L*96);
  float* temb  = alloc(64);
  float* sbuf  = alloc((size_t)N*48);
  float* ef    = alloc((size_t)E*32);
  float* a_s   = alloc((size_t)N*48);
  _Float16* m2h = (_Float16*)alloc((size_t)L*E*128/2 + 64);
  _Float16* wbh = (_Float16*)alloc((size_t)L*NKB*1536/2 + 64);
  _Float16* w1p = (_Float16*)alloc((size_t)L*4096/2 + 64);
  _Float16* w2p = (_Float16*)alloc((size_t)L*16384/2 + 64);

  hipMemsetAsync(degf, 0, ((size_t)N + (size_t)N*48 + (size_t)L*96 + 192)*sizeof(float), stream);
  k_pack2<<<L*51,256,0,stream>>>(conv_w3, conv_b3, conv_w1, conv_w2, wbh, w1p, w2p, L);
  k_encall<<<N+1,128,0,stream>>>(protein_features, ligand_features, Nl,
                               pe_w1, pe_b1, pe_ln_g, pe_ln_b, pe_w2, pe_b2,
                               le_w1, le_b1, le_ln_g, le_ln_b, le_w2, le_b2,
                               sp_w, sp_b, emb_w, sbuf,
                               N, t_in, te_w1, te_b1, te_w2, te_b2, te_ln_g, te_ln_b, temb);
  k_edge<<<(E+1)/2,64,0,stream>>>(ligand_coords, protein_coords, edge_src, edge_dst, temb,
                                  ee_w1, ee_b1, ee_w2, ee_b2, ef, degf, E, Nl);
  dim3 mlpg(E/64, L);
  k_mlp2<<<mlpg,256,0,stream>>>(ef, w1p, conv_b1, w2p, conv_b2, m2h, E);

  dim3 mgrid(E/64, KSPL);
  for (int l=0;l<L;l++){
    const float* bnlp = (l>0) ? (bnb + (l-1)*96) : bnb;
    const float* gp   = (l>0) ? (bn_gs + (l-1)*48) : bn_gs;
    const float* bp   = (l>0) ? (bn_bs + (l-1)*48) : bn_bs;
    int apply = (l>0) ? 1 : 0;
    k_msg7<<<mgrid,256,0,stream>>>(m2h + (size_t)l*E*128, sbuf, a_s, bnlp, gp, bp, apply, N,
                                   wbh + (size_t)l*NKB*1536, edge_src, edge_dst, Sacc, Nl);
    k_node3<<<N/16,256,0,stream>>>(Sacc, degf, sbuf, si_ws + (size_t)l*2304, a_s,
                                   bnlp, gp, bp, apply, bnb + l*96, N);
  }
  k_out2<<<Nl,256,0,stream>>>(sbuf, a_s, bnb + (L-1)*96, bn_gs + (L-1)*48, bn_bs + (L-1)*48,
                              N, out_ws, (float*)d_out);
}